// Round 7
// baseline (227.897 us; speedup 1.0000x reference)
//
#include <hip/hip_runtime.h>
#include <hip/hip_bf16.h>
#include <math.h>

// Problem constants
#define B    8
#define C4   64
#define CQ   16
#define NN   512
#define L4   12
#define NCH1 8            // n's per k1 block
#define KSPL 4            // K-split in pass-2 GEMM
#define KT   128          // k-tile in final kernel

// workspace layout (float offsets)
#define O_T    0                              // T[b][n][c][q] (m=c*16+q)   4194304
#define O_FL   (O_T + (size_t)B*NN*C4*CQ)     // Fl[b][q][k]                  65536
#define O_XX   (O_FL + (size_t)B*CQ*NN)       // [B][CQ]                        128
#define O_YY   (O_XX + B*CQ)                  //                                128
#define O_L2   (O_YY + B*CQ)                  // [B] 1/l2 (+pad)                 16
#define O_AMAX (O_L2 + 16)                    // A[b][n][k]                 2097152
#define O_WARR (O_AMAX + (size_t)B*NN*NN)     // W[b][n][k]=A[b][k][n]      2097152
#define O_PART (O_WARR + (size_t)B*NN*NN)     // [B][KSPL][C4][NN]          1048576

// K1: Fc, Fl, norms, and T[n,c,q] = sum_j Fc[q,n,j]*x[c,n,j]
__global__ __launch_bounds__(256) void k1_fc(const float* __restrict__ x,
                                             const float* __restrict__ Wc,
                                             const float* __restrict__ bc,
                                             float* __restrict__ ws) {
  int blk = blockIdx.x;                // b*64 + nchunk
  int b = blk >> 6;
  int n0 = (blk & 63) * NCH1;
  int t = threadIdx.x;
  __shared__ __align__(16) float xs[C4*NCH1*L4];   // [c][nl][j] 6144
  __shared__ float wcs[CQ*C4];                     // [q][c]
  __shared__ float bcs[CQ];
  __shared__ __align__(16) float fcs[NCH1*CQ*L4];  // [nl][q][j] 1536

  for (int e = t; e < CQ*C4; e += 256) wcs[e] = Wc[e];
  if (t < CQ) bcs[t] = bc[t];
  const float* xb = x + (size_t)b*C4*NN*L4 + (size_t)n0*L4;
  for (int f = t; f < (C4*NCH1*L4)/4; f += 256) {
    int c = f / (NCH1*L4/4);
    int r = f - c*(NCH1*L4/4);
    float4 v = *(const float4*)(xb + (size_t)c*NN*L4 + r*4);
    *(float4*)(xs + c*(NCH1*L4) + r*4) = v;
  }
  __syncthreads();
  for (int e = t; e < NCH1*CQ*L4; e += 256) {
    int nl = e / (CQ*L4);
    int rem = e - nl*(CQ*L4);
    int q = rem / L4, j = rem - q*L4;
    float acc = bcs[q];
    #pragma unroll
    for (int c = 0; c < C4; ++c) acc += wcs[q*C4 + c] * xs[c*(NCH1*L4) + nl*L4 + j];
    fcs[e] = acc;
    if (j == L4-1) ws[O_FL + ((size_t)b*CQ + q)*NN + n0 + nl] = acc;
  }
  __syncthreads();
  if (t < CQ) {
    float yy = 0.f, xx = 0.f;
    for (int nl = 0; nl < NCH1; ++nl) {
      #pragma unroll
      for (int j = 0; j < L4; ++j) { float v = fcs[nl*(CQ*L4) + t*L4 + j]; yy += v*v; }
      float w = fcs[nl*(CQ*L4) + t*L4 + (L4-1)];
      xx += w*w;
    }
    atomicAdd(ws + O_YY + b*CQ + t, yy);
    atomicAdd(ws + O_XX + b*CQ + t, xx);
  }
  {
    int c = t >> 2, q0 = (t & 3) * 4;
    for (int nl = 0; nl < NCH1; ++nl) {
      float xr[L4];
      *(float4*)&xr[0] = *(const float4*)(xs + c*(NCH1*L4) + nl*L4);
      *(float4*)&xr[4] = *(const float4*)(xs + c*(NCH1*L4) + nl*L4 + 4);
      *(float4*)&xr[8] = *(const float4*)(xs + c*(NCH1*L4) + nl*L4 + 8);
      float4 tv; float* tvp = (float*)&tv;
      #pragma unroll
      for (int i = 0; i < 4; ++i) {
        float a = 0.f;
        #pragma unroll
        for (int j = 0; j < L4; ++j) a += fcs[nl*(CQ*L4) + (q0+i)*L4 + j] * xr[j];
        tvp[i] = a;
      }
      *(float4*)(ws + O_T + ((size_t)b*NN + n0 + nl)*(C4*CQ) + t*4) = tv;
    }
  }
}

// K1b: l2inv[b]
__global__ void k1b_l2(float* __restrict__ ws) {
  int t = threadIdx.x;              // 128 threads = B*CQ
  __shared__ float s[B*CQ];
  s[t] = sqrtf(ws[O_XX + t]) * sqrtf(ws[O_YY + t]);
  __syncthreads();
  if (t < B) {
    float sum = 0.f;
    #pragma unroll
    for (int q = 0; q < CQ; ++q) sum += s[t*CQ + q];
    ws[O_L2 + t] = 1.0f / sum;
  }
}

// K2 (pass 1): LDS-free. Block = (b, npair); wave w -> n = npair*2 + (w>>1),
// khalf = w&1. Lane owns k = khalf*256 + lane*4. Fl slice lives in 64 VGPRs;
// T rows read via wave-uniform loads (scalar path). No barriers.
__global__ __launch_bounds__(256, 4) void k2_amax(float* __restrict__ ws) {
  int id = blockIdx.x;              // b*256 + npair
  int b = id >> 8;
  int npair = id & 255;
  int t = threadIdx.x;
  int w = __builtin_amdgcn_readfirstlane(t >> 6);
  int lane = t & 63;
  int n = npair*2 + (w >> 1);
  int k0 = (w & 1)*256 + lane*4;
  const float* flb = ws + O_FL + (size_t)b*CQ*NN + k0;
  float fl[CQ][4];
  #pragma unroll
  for (int q = 0; q < CQ; ++q) *(float4*)fl[q] = *(const float4*)(flb + (size_t)q*NN);
  const float* Tn = ws + O_T + ((size_t)b*NN + n)*1024;
  float l2inv = ws[O_L2 + b];
  float m[4] = {-INFINITY, -INFINITY, -INFINITY, -INFINITY};
  for (int c = 0; c < C4; ++c) {
    float tv[CQ];
    #pragma unroll
    for (int g = 0; g < 4; ++g)
      *(float4*)&tv[g*4] = *(const float4*)(Tn + c*CQ + g*4);   // wave-uniform
    float d[4] = {0.f, 0.f, 0.f, 0.f};
    #pragma unroll
    for (int q = 0; q < CQ; ++q)
      #pragma unroll
      for (int j = 0; j < 4; ++j) d[j] = fmaf(tv[q], fl[q][j], d[j]);
    #pragma unroll
    for (int j = 0; j < 4; ++j) m[j] = fmaxf(m[j], d[j]);
  }
  float o[4];
  #pragma unroll
  for (int j = 0; j < 4; ++j) o[j] = fmaxf(tanhf(m[j]*l2inv), 0.f);
  *(float4*)(ws + O_AMAX + ((size_t)b*NN + n)*NN + k0) = *(float4*)o;
}

// K2b: W[b][n][k] = A[b][k][n]
__global__ __launch_bounds__(256) void k2b_tr(float* __restrict__ ws) {
  int blk = blockIdx.x;             // b*256 + bi*16 + bj
  int b  = blk >> 8;
  int bi = (blk >> 4) & 15;
  int bj = blk & 15;
  int t = threadIdx.x;
  int tx = t & 31, ty = t >> 5;
  __shared__ float tile[32][33];
  const float* am = ws + O_AMAX + (size_t)b*NN*NN;
  float* wa = ws + O_WARR + (size_t)b*NN*NN;
  #pragma unroll
  for (int i = 0; i < 4; ++i) {
    int row = ty + i*8;
    tile[row][tx] = am[(size_t)(bi*32+row)*NN + bj*32 + tx];
  }
  __syncthreads();
  #pragma unroll
  for (int i = 0; i < 4; ++i) {
    int row = ty + i*8;
    wa[(size_t)(bj*32+row)*NN + bi*32 + tx] = tile[tx][row];
  }
}

// K3 (pass 2): LDS-free. Grid ((b*4+ks)*2+kb)*16+mb = 1024 blocks.
// Wave w -> c = mb*4 + w (T rows wave-uniform); lane owns k = kb*256+lane*4
// (one coalesced dwordx4 of W per nl; 4 waves share rows via L1).
// acc[16][4] = 64 VGPR. Epilogue q-reduce with Fl*l2inv, intra-wave.
__global__ __launch_bounds__(256, 4) void k3_gemm(float* __restrict__ ws) {
  int id = blockIdx.x;
  int mb = id & 15;
  int kb = (id >> 4) & 1;
  int ks = (id >> 5) & 3;
  int b  = id >> 7;
  int t = threadIdx.x;
  int w = __builtin_amdgcn_readfirstlane(t >> 6);
  int lane = t & 63;
  int c = mb*4 + w;
  int k0 = kb*256 + lane*4;
  const float* Tc = ws + O_T + ((size_t)b*NN + ks*128)*1024 + c*CQ;
  const float* Wk = ws + O_WARR + ((size_t)b*NN + ks*128)*NN + k0;
  float acc[CQ][4];
  #pragma unroll
  for (int q = 0; q < CQ; ++q)
    #pragma unroll
    for (int j = 0; j < 4; ++j) acc[q][j] = 0.f;

  for (int nl = 0; nl < 128; ++nl) {
    float tv[CQ];
    #pragma unroll
    for (int g = 0; g < 4; ++g)
      *(float4*)&tv[g*4] = *(const float4*)(Tc + (size_t)nl*1024 + g*4);  // wave-uniform
    float wf[4];
    *(float4*)wf = *(const float4*)(Wk + (size_t)nl*NN);
    #pragma unroll
    for (int q = 0; q < CQ; ++q)
      #pragma unroll
      for (int j = 0; j < 4; ++j) acc[q][j] = fmaf(tv[q], wf[j], acc[q][j]);
  }
  // epilogue: s[k] = l2inv * sum_q Fl[q][k]*acc[q][k]
  float l2inv = ws[O_L2 + b];
  const float* flb = ws + O_FL + (size_t)b*CQ*NN + k0;
  float s[4] = {0.f, 0.f, 0.f, 0.f};
  #pragma unroll
  for (int q = 0; q < CQ; ++q) {
    float f[4];
    *(float4*)f = *(const float4*)(flb + (size_t)q*NN);
    #pragma unroll
    for (int j = 0; j < 4; ++j) s[j] += f[j]*acc[q][j];
  }
  #pragma unroll
  for (int j = 0; j < 4; ++j) s[j] *= l2inv;
  float* outp = ws + O_PART + (((size_t)(b*KSPL + ks)*C4 + c)*NN) + k0;
  *(float4*)outp = *(float4*)s;
}

// K4: reduce KSPL partials -> xg, then Fg = W_gcn xg + b_gcn
__global__ __launch_bounds__(256) void k4_out(const float* __restrict__ Wg,
                                              const float* __restrict__ bg,
                                              const float* __restrict__ ws,
                                              float* __restrict__ out) {
  int blk = blockIdx.x;             // b*4 + kc
  int b = blk >> 2, kc = blk & 3;
  int t = threadIdx.x;
  __shared__ float xg[C4][KT+1];
  __shared__ float wg[C4*C4];
  for (int e = t; e < C4*C4; e += 256) wg[e] = Wg[e];
  for (int e = t; e < C4*KT; e += 256) {
    int c = e >> 7, kk = e & (KT-1);
    float s = 0.f;
    #pragma unroll
    for (int chn = 0; chn < KSPL; ++chn)
      s += ws[O_PART + (((size_t)(b*KSPL + chn)*C4 + c)*NN) + kc*KT + kk];
    xg[c][kk] = s;
  }
  __syncthreads();
  int kk = t & (KT-1);
  int ohalf = t >> 7;
  for (int oi = 0; oi < 32; ++oi) {
    int o = ohalf*32 + oi;
    float acc = bg[o];
    #pragma unroll
    for (int c = 0; c < C4; ++c) acc += wg[o*C4 + c] * xg[c][kk];
    out[((size_t)(b*C4 + o))*NN + kc*KT + kk] = acc;
  }
}

extern "C" void kernel_launch(void* const* d_in, const int* in_sizes, int n_in,
                              void* d_out, int out_size, void* d_ws, size_t ws_size,
                              hipStream_t stream) {
  const float* x  = (const float*)d_in[0];
  const float* Wc = (const float*)d_in[1];
  const float* bc = (const float*)d_in[2];
  const float* Wg = (const float*)d_in[3];
  const float* bg = (const float*)d_in[4];
  float* ws  = (float*)d_ws;
  float* out = (float*)d_out;

  hipMemsetAsync(ws + O_XX, 0, (2*B*CQ + 16)*sizeof(float), stream);

  k1_fc  <<<B*64,        256, 0, stream>>>(x, Wc, bc, ws);
  k1b_l2 <<<1,           128, 0, stream>>>(ws);
  k2_amax<<<B*256,       256, 0, stream>>>(ws);
  k2b_tr <<<B*16*16,     256, 0, stream>>>(ws);
  k3_gemm<<<B*KSPL*2*16, 256, 0, stream>>>(ws);
  k4_out <<<B*4,         256, 0, stream>>>(Wg, bg, ws, out);
}

// Round 9
// 193.030 us; speedup vs baseline: 1.1806x; 1.1806x over previous
//
#include <hip/hip_runtime.h>
#include <hip/hip_bf16.h>
#include <math.h>

// Problem constants
#define B    8
#define C4   64
#define CQ   16
#define NN   512
#define L4   12
#define NCH1 8            // n's per k1 block
#define KT   128          // k-tile in final kernel

// workspace layout (float offsets)
#define O_T    0                                   // T[b][n][m] fp32          4194304
#define O_TH   (O_T + (size_t)B*NN*C4*CQ)          // Thi bf16 [b][m][n]       2097152
#define O_TL   (O_TH + (size_t)B*1024*NN/2)        // Tlo bf16 [b][m][n]       2097152
#define O_FL   (O_TL + (size_t)B*1024*NN/2)        // Fl[b][q][k]                65536
#define O_XX   (O_FL + (size_t)B*CQ*NN)            // [B][CQ]                      128
#define O_YY   (O_XX + B*CQ)                       //                              128
#define O_L2   (O_YY + B*CQ)                       // [B] 1/l2 (+pad)               16
#define O_AMAX (O_L2 + 16)                         // A[b][n][k] fp32          2097152
#define O_AH   (O_AMAX + (size_t)B*NN*NN)          // Ahi bf16 [b][n][k]       1048576
#define O_AL   (O_AH + (size_t)B*NN*NN/2)          // Alo bf16 [b][n][k]       1048576
#define O_XG   (O_AL + (size_t)B*NN*NN/2)          // xg[b][c][k]               262144

typedef __attribute__((ext_vector_type(8))) short short8;
typedef __attribute__((ext_vector_type(4))) float floatx4;

__device__ inline void split2(float x0, float x1, uint& hw, uint& lw) {
  uint u0 = __float_as_uint(x0), u1 = __float_as_uint(x1);
  uint h0 = u0 >> 16, h1 = u1 >> 16;
  float r0 = x0 - __uint_as_float(h0 << 16);
  float r1 = x1 - __uint_as_float(h1 << 16);
  hw = h0 | (h1 << 16);
  lw = (__float_as_uint(r0) >> 16) | ((__float_as_uint(r1) >> 16) << 16);
}

// K1: Fc, Fl, norms, T[n,m] fp32, and Thi/Tlo bf16 planes [m][n]
__global__ __launch_bounds__(256) void k1_fc(const float* __restrict__ x,
                                             const float* __restrict__ Wc,
                                             const float* __restrict__ bc,
                                             float* __restrict__ ws) {
  int blk = blockIdx.x;                // b*64 + nchunk
  int b = blk >> 6;
  int n0 = (blk & 63) * NCH1;
  int t = threadIdx.x;
  __shared__ __align__(16) float xs[C4*NCH1*L4];   // [c][nl][j] 6144
  __shared__ float wcs[CQ*C4];                     // [q][c]
  __shared__ float bcs[CQ];
  __shared__ __align__(16) float fcs[NCH1*CQ*L4];  // [nl][q][j] 1536

  for (int e = t; e < CQ*C4; e += 256) wcs[e] = Wc[e];
  if (t < CQ) bcs[t] = bc[t];
  const float* xb = x + (size_t)b*C4*NN*L4 + (size_t)n0*L4;
  for (int f = t; f < (C4*NCH1*L4)/4; f += 256) {
    int c = f / (NCH1*L4/4);
    int r = f - c*(NCH1*L4/4);
    float4 v = *(const float4*)(xb + (size_t)c*NN*L4 + r*4);
    *(float4*)(xs + c*(NCH1*L4) + r*4) = v;
  }
  __syncthreads();
  for (int e = t; e < NCH1*CQ*L4; e += 256) {
    int nl = e / (CQ*L4);
    int rem = e - nl*(CQ*L4);
    int q = rem / L4, j = rem - q*L4;
    float acc = bcs[q];
    #pragma unroll
    for (int c = 0; c < C4; ++c) acc += wcs[q*C4 + c] * xs[c*(NCH1*L4) + nl*L4 + j];
    fcs[e] = acc;
    if (j == L4-1) ws[O_FL + ((size_t)b*CQ + q)*NN + n0 + nl] = acc;
  }
  __syncthreads();
  if (t < CQ) {
    float yy = 0.f, xx = 0.f;
    for (int nl = 0; nl < NCH1; ++nl) {
      #pragma unroll
      for (int j = 0; j < L4; ++j) { float v = fcs[nl*(CQ*L4) + t*L4 + j]; yy += v*v; }
      float w = fcs[nl*(CQ*L4) + t*L4 + (L4-1)];
      xx += w*w;
    }
    atomicAdd(ws + O_YY + b*CQ + t, yy);
    atomicAdd(ws + O_XX + b*CQ + t, xx);
  }
  {
    int c = t >> 2, q0 = (t & 3) * 4;
    float vals[4][NCH1];
    for (int nl = 0; nl < NCH1; ++nl) {
      float xr[L4];
      *(float4*)&xr[0] = *(const float4*)(xs + c*(NCH1*L4) + nl*L4);
      *(float4*)&xr[4] = *(const float4*)(xs + c*(NCH1*L4) + nl*L4 + 4);
      *(float4*)&xr[8] = *(const float4*)(xs + c*(NCH1*L4) + nl*L4 + 8);
      float4 tv; float* tvp = (float*)&tv;
      #pragma unroll
      for (int i = 0; i < 4; ++i) {
        float a = 0.f;
        #pragma unroll
        for (int j = 0; j < L4; ++j) a += fcs[nl*(CQ*L4) + (q0+i)*L4 + j] * xr[j];
        tvp[i] = a;
        vals[i][nl] = a;
      }
      *(float4*)(ws + O_T + ((size_t)b*NN + n0 + nl)*(C4*CQ) + t*4) = tv;
    }
    ushort* TH = (ushort*)(ws + O_TH);
    ushort* TL = (ushort*)(ws + O_TL);
    #pragma unroll
    for (int i = 0; i < 4; ++i) {
      int m = c*16 + q0 + i;
      uint hw[4], lw[4];
      #pragma unroll
      for (int jj = 0; jj < 4; ++jj)
        split2(vals[i][2*jj], vals[i][2*jj+1], hw[jj], lw[jj]);
      size_t off = ((size_t)b*1024 + m)*NN + n0;   // ushort index
      *(uint4*)(TH + off) = make_uint4(hw[0], hw[1], hw[2], hw[3]);
      *(uint4*)(TL + off) = make_uint4(lw[0], lw[1], lw[2], lw[3]);
    }
  }
}

// K1b: l2inv[b]
__global__ void k1b_l2(float* __restrict__ ws) {
  int t = threadIdx.x;              // 128 threads = B*CQ
  __shared__ float s[B*CQ];
  s[t] = sqrtf(ws[O_XX + t]) * sqrtf(ws[O_YY + t]);
  __syncthreads();
  if (t < B) {
    float sum = 0.f;
    #pragma unroll
    for (int q = 0; q < CQ; ++q) sum += s[t*CQ + q];
    ws[O_L2 + t] = 1.0f / sum;
  }
}

// K2 (pass 1, unchanged from R6 known-good): one block per (b,n).
__global__ __launch_bounds__(256, 2) void k2_amax(float* __restrict__ ws) {
  int bn = blockIdx.x;              // b*512 + n
  int b = bn >> 9;
  int t = threadIdx.x;
  int w = t >> 6;
  int lane = t & 63;
  __shared__ __align__(16) float Tt[16*64];     // [q][c]
  __shared__ __align__(16) float Fls[16*512];   // [q][k]
  __shared__ __align__(16) float red[3*512];
  {
    float4 v = *(const float4*)(ws + O_T + (size_t)bn*1024 + t*4);
    int c = t >> 2, q0 = (t & 3) * 4;
    Tt[ q0   *64 + c] = v.x;
    Tt[(q0+1)*64 + c] = v.y;
    Tt[(q0+2)*64 + c] = v.z;
    Tt[(q0+3)*64 + c] = v.w;
  }
  const float* flb = ws + O_FL + (size_t)b*CQ*NN;
  #pragma unroll
  for (int i = 0; i < 8; ++i) {
    int f = t + 256*i;              // 2048 float4s: [q][512]
    int q = f >> 7, col = (f & 127) * 4;
    *(float4*)(Fls + q*512 + col) = *(const float4*)(flb + (size_t)q*NN + col);
  }
  float l2inv = ws[O_L2 + b];
  __syncthreads();
  float acc[16][8];
  #pragma unroll
  for (int i = 0; i < 16; ++i)
    #pragma unroll
    for (int j = 0; j < 8; ++j) acc[i][j] = 0.f;
  #pragma unroll
  for (int q = 0; q < 16; ++q) {
    float a[16], b0[4], b1[4];
    #pragma unroll
    for (int g = 0; g < 4; ++g)
      *(float4*)&a[g*4] = *(const float4*)&Tt[q*64 + w*16 + g*4];   // broadcast
    *(float4*)b0 = *(const float4*)&Fls[q*512 + lane*4];
    *(float4*)b1 = *(const float4*)&Fls[q*512 + 256 + lane*4];
    #pragma unroll
    for (int i = 0; i < 16; ++i) {
      #pragma unroll
      for (int j = 0; j < 4; ++j) {
        acc[i][j]   += a[i]*b0[j];
        acc[i][4+j] += a[i]*b1[j];
      }
    }
  }
  float m[8];
  #pragma unroll
  for (int j = 0; j < 8; ++j) {
    float mm = acc[0][j];
    #pragma unroll
    for (int i = 1; i < 16; ++i) mm = fmaxf(mm, acc[i][j]);
    m[j] = mm;
  }
  if (w > 0) {
    *(float4*)&red[(w-1)*512 + lane*4]       = *(float4*)&m[0];
    *(float4*)&red[(w-1)*512 + 256 + lane*4] = *(float4*)&m[4];
  }
  __syncthreads();
  if (w == 0) {
    #pragma unroll
    for (int g = 0; g < 3; ++g) {
      float4 p0 = *(const float4*)&red[g*512 + lane*4];
      float4 p1 = *(const float4*)&red[g*512 + 256 + lane*4];
      m[0] = fmaxf(m[0], p0.x); m[1] = fmaxf(m[1], p0.y);
      m[2] = fmaxf(m[2], p0.z); m[3] = fmaxf(m[3], p0.w);
      m[4] = fmaxf(m[4], p1.x); m[5] = fmaxf(m[5], p1.y);
      m[6] = fmaxf(m[6], p1.z); m[7] = fmaxf(m[7], p1.w);
    }
    float o[8];
    #pragma unroll
    for (int j = 0; j < 8; ++j) o[j] = fmaxf(tanhf(m[j]*l2inv), 0.f);
    float* am = ws + O_AMAX + (size_t)bn*NN;
    *(float4*)(am + lane*4)       = *(float4*)&o[0];
    *(float4*)(am + 256 + lane*4) = *(float4*)&o[4];
  }
}

// K2c: stream-convert A fp32 -> Ahi/Alo bf16 planes (same [b][n][k] layout)
__global__ __launch_bounds__(256) void k2c_cvt(float* __restrict__ ws) {
  size_t base = ((size_t)blockIdx.x * 256 + threadIdx.x) * 8;
  const float* A = ws + O_AMAX;
  ushort* AH = (ushort*)(ws + O_AH);
  ushort* AL = (ushort*)(ws + O_AL);
  float v[8];
  *(float4*)&v[0] = *(const float4*)(A + base);
  *(float4*)&v[4] = *(const float4*)(A + base + 4);
  uint hw[4], lw[4];
  #pragma unroll
  for (int jj = 0; jj < 4; ++jj) split2(v[2*jj], v[2*jj+1], hw[jj], lw[jj]);
  *(uint4*)(AH + base) = make_uint4(hw[0], hw[1], hw[2], hw[3]);
  *(uint4*)(AL + base) = make_uint4(lw[0], lw[1], lw[2], lw[3]);
}

// K3 (pass 2, MFMA split-bf16): U[m,k] = sum_n T[n,m]*W[n,k], W[n,k]=A[k,n]
// (so B-frag reads contiguous elements of stored-A row k). Block: 128m x 64k,
// full n in-loop (16 K-steps of 32). Waves 2x2, each 64m x 32k = 4x2 tiles of
// 16x16x32; 3 MFMAs/tile (hh, hl, lh). Epilogue: q-fold with Fl, shfl_xor
// quad-reduce, write xg[b][c][k] directly.
__global__ __launch_bounds__(256, 2) void k3_mfma(float* __restrict__ ws) {
  int id = blockIdx.x;             // b*64 + mbb*8 + kb
  int kb = id & 7;
  int mbb = (id >> 3) & 7;
  int b = id >> 6;
  int t = threadIdx.x;
  int lane = t & 63;
  int w = t >> 6;
  int mw = w >> 1, kw = w & 1;
  int row = lane & 15, quad = lane >> 4;

  __shared__ __align__(16) ushort Ah[128*32];
  __shared__ __align__(16) ushort Al[128*32];
  __shared__ __align__(16) ushort Bh[64*32];
  __shared__ __align__(16) ushort Bl[64*32];

  const ushort* TH = (const ushort*)(ws + O_TH) + ((size_t)b*1024 + mbb*128)*NN;
  const ushort* TL = (const ushort*)(ws + O_TL) + ((size_t)b*1024 + mbb*128)*NN;
  const ushort* AHp = (const ushort*)(ws + O_AH) + ((size_t)b*NN + kb*64)*NN;
  const ushort* ALp = (const ushort*)(ws + O_AL) + ((size_t)b*NN + kb*64)*NN;

  floatx4 acc[4][2];
  #pragma unroll
  for (int i = 0; i < 4; ++i)
    #pragma unroll
    for (int j = 0; j < 2; ++j) acc[i][j] = (floatx4){0.f, 0.f, 0.f, 0.f};

  for (int ksx = 0; ksx < 16; ++ksx) {
    int p0 = ksx*32;
    __syncthreads();
    #pragma unroll
    for (int i = 0; i < 2; ++i) {       // A: 128 rows x 32 n, hi+lo
      int f = t + 256*i;
      int m = f >> 2, seg = (f & 3) * 8;
      *(uint4*)(Ah + m*32 + seg) = *(const uint4*)(TH + (size_t)m*NN + p0 + seg);
      *(uint4*)(Al + m*32 + seg) = *(const uint4*)(TL + (size_t)m*NN + p0 + seg);
    }
    {                                   // B: 64 rows x 32 n, hi+lo
      int j = t >> 2, seg = (t & 3) * 8;
      *(uint4*)(Bh + j*32 + seg) = *(const uint4*)(AHp + (size_t)j*NN + p0 + seg);
      *(uint4*)(Bl + j*32 + seg) = *(const uint4*)(ALp + (size_t)j*NN + p0 + seg);
    }
    __syncthreads();
    short8 bh[2], bl[2];
    #pragma unroll
    for (int kt = 0; kt < 2; ++kt) {
      int jrow = kw*32 + kt*16 + row;
      bh[kt] = *(const short8*)(Bh + jrow*32 + quad*8);
      bl[kt] = *(const short8*)(Bl + jrow*32 + quad*8);
    }
    #pragma unroll
    for (int mt = 0; mt < 4; ++mt) {
      int mrow = mw*64 + mt*16 + row;
      short8 ah = *(const short8*)(Ah + mrow*32 + quad*8);
      short8 al = *(const short8*)(Al + mrow*32 + quad*8);
      #pragma unroll
      for (int kt = 0; kt < 2; ++kt) {
        acc[mt][kt] = __builtin_amdgcn_mfma_f32_16x16x32_bf16(ah, bh[kt], acc[mt][kt], 0, 0, 0);
        acc[mt][kt] = __builtin_amdgcn_mfma_f32_16x16x32_bf16(ah, bl[kt], acc[mt][kt], 0, 0, 0);
        acc[mt][kt] = __builtin_amdgcn_mfma_f32_16x16x32_bf16(al, bh[kt], acc[mt][kt], 0, 0, 0);
      }
    }
  }
  // epilogue: m-tile = one c (rows are q). s = sum_q Fl[q,k]*U[(c,q),k] * l2inv
  float l2inv = ws[O_L2 + b];
  const float* flb = ws + O_FL + (size_t)b*CQ*NN;
  float fl[2][4];
  #pragma unroll
  for (int kt = 0; kt < 2; ++kt) {
    int kcol = kb*64 + kw*32 + kt*16 + row;
    #pragma unroll
    for (int rg = 0; rg < 4; ++rg)
      fl[kt][rg] = flb[(size_t)(quad*4 + rg)*NN + kcol];
  }
  #pragma unroll
  for (int mt = 0; mt < 4; ++mt) {
    int c = mbb*8 + mw*4 + mt;
    #pragma unroll
    for (int kt = 0; kt < 2; ++kt) {
      float s = fl[kt][0]*acc[mt][kt][0] + fl[kt][1]*acc[mt][kt][1]
              + fl[kt][2]*acc[mt][kt][2] + fl[kt][3]*acc[mt][kt][3];
      s += __shfl_xor(s, 32);
      s += __shfl_xor(s, 16);
      if (quad == 0) {
        int kcol = kb*64 + kw*32 + kt*16 + row;
        ws[O_XG + ((size_t)b*C4 + c)*NN + kcol] = s * l2inv;
      }
    }
  }
}

// K4: Fg = W_gcn xg + b_gcn (xg already reduced)
__global__ __launch_bounds__(256) void k4_out(const float* __restrict__ Wg,
                                              const float* __restrict__ bg,
                                              const float* __restrict__ ws,
                                              float* __restrict__ out) {
  int blk = blockIdx.x;             // b*4 + kc
  int b = blk >> 2, kc = blk & 3;
  int t = threadIdx.x;
  __shared__ float xg[C4][KT+1];
  __shared__ float wg[C4*C4];
  for (int e = t; e < C4*C4; e += 256) wg[e] = Wg[e];
  for (int e = t; e < C4*KT; e += 256) {
    int c = e >> 7, kk = e & (KT-1);
    xg[c][kk] = ws[O_XG + ((size_t)(b*C4 + c))*NN + kc*KT + kk];
  }
  __syncthreads();
  int kk = t & (KT-1);
  int ohalf = t >> 7;
  for (int oi = 0; oi < 32; ++oi) {
    int o = ohalf*32 + oi;
    float acc = bg[o];
    #pragma unroll
    for (int c = 0; c < C4; ++c) acc += wg[o*C4 + c] * xg[c][kk];
    out[((size_t)(b*C4 + o))*NN + kc*KT + kk] = acc;
  }
}

extern "C" void kernel_launch(void* const* d_in, const int* in_sizes, int n_in,
                              void* d_out, int out_size, void* d_ws, size_t ws_size,
                              hipStream_t stream) {
  const float* x  = (const float*)d_in[0];
  const float* Wc = (const float*)d_in[1];
  const float* bc = (const float*)d_in[2];
  const float* Wg = (const float*)d_in[3];
  const float* bg = (const float*)d_in[4];
  float* ws  = (float*)d_ws;
  float* out = (float*)d_out;

  hipMemsetAsync(ws + O_XX, 0, (2*B*CQ + 16)*sizeof(float), stream);

  k1_fc   <<<B*64,   256, 0, stream>>>(x, Wc, bc, ws);
  k1b_l2  <<<1,      128, 0, stream>>>(ws);
  k2_amax <<<B*NN,   256, 0, stream>>>(ws);
  k2c_cvt <<<1024,   256, 0, stream>>>(ws);
  k3_mfma <<<B*64,   256, 0, stream>>>(ws);
  k4_out  <<<B*4,    256, 0, stream>>>(Wg, bg, ws, out);
}

// Round 10
// 190.244 us; speedup vs baseline: 1.1979x; 1.0146x over previous
//
#include <hip/hip_runtime.h>
#include <hip/hip_bf16.h>
#include <math.h>

// Problem constants
#define B    8
#define C4   64
#define CQ   16
#define NN   512
#define L4   12
#define NCH1 8            // n's per k1 block
#define KT   128          // k-tile in final kernel

// workspace layout (float offsets)
#define O_TH   0                                   // Thi bf16 [b][m][n]      2097152
#define O_TL   (O_TH + (size_t)B*1024*NN/2)        // Tlo bf16 [b][m][n]      2097152
#define O_T2H  (O_TL + (size_t)B*1024*NN/2)        // Thi bf16 [b][n][m]      2097152
#define O_T2L  (O_T2H + (size_t)B*NN*1024/2)       // Tlo bf16 [b][n][m]      2097152
#define O_FL   (O_T2L + (size_t)B*NN*1024/2)       // Fl[b][q][k] fp32          65536
#define O_FLTH (O_FL + (size_t)B*CQ*NN)            // Flt hi bf16 [b][k][32]    65536
#define O_FLTL (O_FLTH + (size_t)B*NN*32/2)        // Flt lo bf16 [b][k][32]    65536
#define O_XX   (O_FLTL + (size_t)B*NN*32/2)        // [B][CQ]                     128
#define O_YY   (O_XX + B*CQ)                       //                             128
#define O_L2   (O_YY + B*CQ)                       // [B] 1/l2 (+pad)              16
#define O_AH   (O_L2 + 16)                         // Ahi bf16 [b][n][k]      1048576
#define O_AL   (O_AH + (size_t)B*NN*NN/2)          // Alo bf16 [b][n][k]      1048576
#define O_XG   (O_AL + (size_t)B*NN*NN/2)          // xg[b][c][k] fp32         262144

typedef __attribute__((ext_vector_type(8))) short short8;
typedef __attribute__((ext_vector_type(4))) float floatx4;

__device__ inline void split2(float x0, float x1, uint& hw, uint& lw) {
  uint u0 = __float_as_uint(x0), u1 = __float_as_uint(x1);
  uint h0 = u0 >> 16, h1 = u1 >> 16;
  float r0 = x0 - __uint_as_float(h0 << 16);
  float r1 = x1 - __uint_as_float(h1 << 16);
  hw = h0 | (h1 << 16);
  lw = (__float_as_uint(r0) >> 16) | ((__float_as_uint(r1) >> 16) << 16);
}

// K1: Fc, Fl, norms, T bf16 split planes in BOTH layouts:
//  TH/TL [m][n] (for k3 staging), T2H/T2L [n][m] (for k2 A-frags).
__global__ __launch_bounds__(256) void k1_fc(const float* __restrict__ x,
                                             const float* __restrict__ Wc,
                                             const float* __restrict__ bc,
                                             float* __restrict__ ws) {
  int blk = blockIdx.x;                // b*64 + nchunk
  int b = blk >> 6;
  int n0 = (blk & 63) * NCH1;
  int t = threadIdx.x;
  __shared__ __align__(16) float xs[C4*NCH1*L4];   // [c][nl][j] 6144
  __shared__ float wcs[CQ*C4];                     // [q][c]
  __shared__ float bcs[CQ];
  __shared__ __align__(16) float fcs[NCH1*CQ*L4];  // [nl][q][j] 1536

  for (int e = t; e < CQ*C4; e += 256) wcs[e] = Wc[e];
  if (t < CQ) bcs[t] = bc[t];
  const float* xb = x + (size_t)b*C4*NN*L4 + (size_t)n0*L4;
  for (int f = t; f < (C4*NCH1*L4)/4; f += 256) {
    int c = f / (NCH1*L4/4);
    int r = f - c*(NCH1*L4/4);
    float4 v = *(const float4*)(xb + (size_t)c*NN*L4 + r*4);
    *(float4*)(xs + c*(NCH1*L4) + r*4) = v;
  }
  __syncthreads();
  for (int e = t; e < NCH1*CQ*L4; e += 256) {
    int nl = e / (CQ*L4);
    int rem = e - nl*(CQ*L4);
    int q = rem / L4, j = rem - q*L4;
    float acc = bcs[q];
    #pragma unroll
    for (int c = 0; c < C4; ++c) acc += wcs[q*C4 + c] * xs[c*(NCH1*L4) + nl*L4 + j];
    fcs[e] = acc;
    if (j == L4-1) ws[O_FL + ((size_t)b*CQ + q)*NN + n0 + nl] = acc;
  }
  __syncthreads();
  if (t < CQ) {
    float yy = 0.f, xx = 0.f;
    for (int nl = 0; nl < NCH1; ++nl) {
      #pragma unroll
      for (int j = 0; j < L4; ++j) { float v = fcs[nl*(CQ*L4) + t*L4 + j]; yy += v*v; }
      float w = fcs[nl*(CQ*L4) + t*L4 + (L4-1)];
      xx += w*w;
    }
    atomicAdd(ws + O_YY + b*CQ + t, yy);
    atomicAdd(ws + O_XX + b*CQ + t, xx);
  }
  {
    int c = t >> 2, q0 = (t & 3) * 4;
    float vals[4][NCH1];
    ushort* T2H = (ushort*)(ws + O_T2H);
    ushort* T2L = (ushort*)(ws + O_T2L);
    for (int nl = 0; nl < NCH1; ++nl) {
      float xr[L4];
      *(float4*)&xr[0] = *(const float4*)(xs + c*(NCH1*L4) + nl*L4);
      *(float4*)&xr[4] = *(const float4*)(xs + c*(NCH1*L4) + nl*L4 + 4);
      *(float4*)&xr[8] = *(const float4*)(xs + c*(NCH1*L4) + nl*L4 + 8);
      float tvp[4];
      #pragma unroll
      for (int i = 0; i < 4; ++i) {
        float a = 0.f;
        #pragma unroll
        for (int j = 0; j < L4; ++j) a += fcs[nl*(CQ*L4) + (q0+i)*L4 + j] * xr[j];
        tvp[i] = a;
        vals[i][nl] = a;
      }
      uint hw0, lw0, hw1, lw1;
      split2(tvp[0], tvp[1], hw0, lw0);
      split2(tvp[2], tvp[3], hw1, lw1);
      size_t off2 = ((size_t)b*NN + n0 + nl)*1024 + t*4;   // ushort index
      *(uint2*)(T2H + off2) = make_uint2(hw0, hw1);
      *(uint2*)(T2L + off2) = make_uint2(lw0, lw1);
    }
    ushort* TH = (ushort*)(ws + O_TH);
    ushort* TL = (ushort*)(ws + O_TL);
    #pragma unroll
    for (int i = 0; i < 4; ++i) {
      int m = c*16 + q0 + i;
      uint hw[4], lw[4];
      #pragma unroll
      for (int jj = 0; jj < 4; ++jj)
        split2(vals[i][2*jj], vals[i][2*jj+1], hw[jj], lw[jj]);
      size_t off = ((size_t)b*1024 + m)*NN + n0;   // ushort index
      *(uint4*)(TH + off) = make_uint4(hw[0], hw[1], hw[2], hw[3]);
      *(uint4*)(TL + off) = make_uint4(lw[0], lw[1], lw[2], lw[3]);
    }
  }
}

// K1b: l2inv[b]
__global__ void k1b_l2(float* __restrict__ ws) {
  int t = threadIdx.x;              // 128 threads = B*CQ
  __shared__ float s[B*CQ];
  s[t] = sqrtf(ws[O_XX + t]) * sqrtf(ws[O_YY + t]);
  __syncthreads();
  if (t < B) {
    float sum = 0.f;
    #pragma unroll
    for (int q = 0; q < CQ; ++q) sum += s[t*CQ + q];
    ws[O_L2 + t] = 1.0f / sum;
  }
}

// K1c: Flt[b][k][32] hi/lo bf16, q in [16,32) zero-padded (annihilates the
// MFMA K-pad). One thread per (b,k).
__global__ __launch_bounds__(256) void k1c_flt(float* __restrict__ ws) {
  int idx = blockIdx.x*256 + threadIdx.x;   // 0..4095 = b*512 + k
  int b = idx >> 9, k = idx & 511;
  const float* fl = ws + O_FL + (size_t)b*CQ*NN + k;
  ushort h[16], l[16];
  #pragma unroll
  for (int q = 0; q < CQ; ++q) {
    float v = fl[(size_t)q*NN];
    uint u = __float_as_uint(v);
    uint hh = u >> 16;
    float r = v - __uint_as_float(hh << 16);
    h[q] = (ushort)hh;
    l[q] = (ushort)(__float_as_uint(r) >> 16);
  }
  ushort* FH = (ushort*)(ws + O_FLTH) + (size_t)idx*32;
  ushort* FLo = (ushort*)(ws + O_FLTL) + (size_t)idx*32;
  *(uint4*)(FH)      = *(uint4*)&h[0];
  *(uint4*)(FH + 8)  = *(uint4*)&h[8];
  *(uint4*)(FH + 16) = make_uint4(0,0,0,0);
  *(uint4*)(FH + 24) = make_uint4(0,0,0,0);
  *(uint4*)(FLo)      = *(uint4*)&l[0];
  *(uint4*)(FLo + 8)  = *(uint4*)&l[8];
  *(uint4*)(FLo + 16) = make_uint4(0,0,0,0);
  *(uint4*)(FLo + 24) = make_uint4(0,0,0,0);
}

// K2 (pass 1, MFMA split-bf16): per (b, 16-n chunk, khalf).
// Per n: R[c 64][k 256-half] via 4 c-tiles x 4 k-tiles of 16x16x32 (K=q,
// padded to 32; pad killed by Flt zeros). max over c in-register + shfl_xor,
// A = relu(tanh(m*l2inv)) -> split -> AH/AL[b][n][k]. No LDS, no barriers.
__global__ __launch_bounds__(256, 2) void k2_mfma(float* __restrict__ ws) {
  int id = blockIdx.x;              // b*64 + nch*2 + kh
  int kh = id & 1;
  int nch = (id >> 1) & 31;
  int b = id >> 6;
  int t = threadIdx.x;
  int w = t >> 6, lane = t & 63;
  int row = lane & 15, quad = lane >> 4;
  float l2inv = ws[O_L2 + b];
  const ushort* FltH = (const ushort*)(ws + O_FLTH);
  const ushort* FltL = (const ushort*)(ws + O_FLTL);
  const ushort* zeroP = FltH + 16;          // 16 zero ushorts (k1c pad)
  // B-frags: 4 k-tiles, hi+lo (resident across the n-loop)
  short8 bhf[4], blf[4];
  int kcol[4];
  #pragma unroll
  for (int kt = 0; kt < 4; ++kt) {
    kcol[kt] = kh*256 + w*64 + kt*16 + row;
    size_t off = ((size_t)(b*NN + kcol[kt]))*32 + quad*8;
    bhf[kt] = *(const short8*)(FltH + off);
    blf[kt] = *(const short8*)(FltL + off);
  }
  const ushort* T2H = (const ushort*)(ws + O_T2H) + ((size_t)b*NN + nch*16)*1024;
  const ushort* T2L = (const ushort*)(ws + O_T2L) + ((size_t)b*NN + nch*16)*1024;
  ushort* AH = (ushort*)(ws + O_AH) + ((size_t)b*NN + nch*16)*NN;
  ushort* AL = (ushort*)(ws + O_AL) + ((size_t)b*NN + nch*16)*NN;

  for (int i = 0; i < 16; ++i) {
    short8 ah[4], al[4];
    #pragma unroll
    for (int ct = 0; ct < 4; ++ct) {
      size_t off = (size_t)i*1024 + (ct*16 + row)*16 + quad*8;
      const ushort* ph = (quad < 2) ? (T2H + off) : zeroP;   // gate K-pad
      const ushort* pl = (quad < 2) ? (T2L + off) : zeroP;
      ah[ct] = *(const short8*)ph;
      al[ct] = *(const short8*)pl;
    }
    floatx4 acc[4][4];
    #pragma unroll
    for (int ct = 0; ct < 4; ++ct)
      #pragma unroll
      for (int kt = 0; kt < 4; ++kt) {
        floatx4 a = (floatx4){0.f, 0.f, 0.f, 0.f};
        a = __builtin_amdgcn_mfma_f32_16x16x32_bf16(ah[ct], bhf[kt], a, 0, 0, 0);
        a = __builtin_amdgcn_mfma_f32_16x16x32_bf16(ah[ct], blf[kt], a, 0, 0, 0);
        a = __builtin_amdgcn_mfma_f32_16x16x32_bf16(al[ct], bhf[kt], a, 0, 0, 0);
        acc[ct][kt] = a;
      }
    #pragma unroll
    for (int kt = 0; kt < 4; ++kt) {
      float m = acc[0][kt][0];
      #pragma unroll
      for (int ct = 0; ct < 4; ++ct)
        #pragma unroll
        for (int rg = 0; rg < 4; ++rg)
          if (ct + rg) m = fmaxf(m, acc[ct][kt][rg]);
      m = fmaxf(m, __shfl_xor(m, 16));
      m = fmaxf(m, __shfl_xor(m, 32));
      float av = fmaxf(tanhf(m*l2inv), 0.f);
      uint u = __float_as_uint(av);
      uint hh = u >> 16;
      float r = av - __uint_as_float(hh << 16);
      ushort lv = (ushort)(__float_as_uint(r) >> 16);
      if (quad == 0) {
        AH[(size_t)i*NN + kcol[kt]] = (ushort)hh;
        AL[(size_t)i*NN + kcol[kt]] = lv;
      }
    }
  }
}

// K3 (pass 2, MFMA split-bf16): unchanged from R9 (passed).
__global__ __launch_bounds__(256, 2) void k3_mfma(float* __restrict__ ws) {
  int id = blockIdx.x;             // b*64 + mbb*8 + kb
  int kb = id & 7;
  int mbb = (id >> 3) & 7;
  int b = id >> 6;
  int t = threadIdx.x;
  int lane = t & 63;
  int w = t >> 6;
  int mw = w >> 1, kw = w & 1;
  int row = lane & 15, quad = lane >> 4;

  __shared__ __align__(16) ushort Ah[128*32];
  __shared__ __align__(16) ushort Al[128*32];
  __shared__ __align__(16) ushort Bh[64*32];
  __shared__ __align__(16) ushort Bl[64*32];

  const ushort* TH = (const ushort*)(ws + O_TH) + ((size_t)b*1024 + mbb*128)*NN;
  const ushort* TL = (const ushort*)(ws + O_TL) + ((size_t)b*1024 + mbb*128)*NN;
  const ushort* AHp = (const ushort*)(ws + O_AH) + ((size_t)b*NN + kb*64)*NN;
  const ushort* ALp = (const ushort*)(ws + O_AL) + ((size_t)b*NN + kb*64)*NN;

  floatx4 acc[4][2];
  #pragma unroll
  for (int i = 0; i < 4; ++i)
    #pragma unroll
    for (int j = 0; j < 2; ++j) acc[i][j] = (floatx4){0.f, 0.f, 0.f, 0.f};

  for (int ksx = 0; ksx < 16; ++ksx) {
    int p0 = ksx*32;
    __syncthreads();
    #pragma unroll
    for (int i = 0; i < 2; ++i) {       // A: 128 rows x 32 n, hi+lo
      int f = t + 256*i;
      int m = f >> 2, seg = (f & 3) * 8;
      *(uint4*)(Ah + m*32 + seg) = *(const uint4*)(TH + (size_t)m*NN + p0 + seg);
      *(uint4*)(Al + m*32 + seg) = *(const uint4*)(TL + (size_t)m*NN + p0 + seg);
    }
    {                                   // B: 64 rows x 32 n, hi+lo
      int j = t >> 2, seg = (t & 3) * 8;
      *(uint4*)(Bh + j*32 + seg) = *(const uint4*)(AHp + (size_t)j*NN + p0 + seg);
      *(uint4*)(Bl + j*32 + seg) = *(const uint4*)(ALp + (size_t)j*NN + p0 + seg);
    }
    __syncthreads();
    short8 bh[2], bl[2];
    #pragma unroll
    for (int kt = 0; kt < 2; ++kt) {
      int jrow = kw*32 + kt*16 + row;
      bh[kt] = *(const short8*)(Bh + jrow*32 + quad*8);
      bl[kt] = *(const short8*)(Bl + jrow*32 + quad*8);
    }
    #pragma unroll
    for (int mt = 0; mt < 4; ++mt) {
      int mrow = mw*64 + mt*16 + row;
      short8 ah = *(const short8*)(Ah + mrow*32 + quad*8);
      short8 al = *(const short8*)(Al + mrow*32 + quad*8);
      #pragma unroll
      for (int kt = 0; kt < 2; ++kt) {
        acc[mt][kt] = __builtin_amdgcn_mfma_f32_16x16x32_bf16(ah, bh[kt], acc[mt][kt], 0, 0, 0);
        acc[mt][kt] = __builtin_amdgcn_mfma_f32_16x16x32_bf16(ah, bl[kt], acc[mt][kt], 0, 0, 0);
        acc[mt][kt] = __builtin_amdgcn_mfma_f32_16x16x32_bf16(al, bh[kt], acc[mt][kt], 0, 0, 0);
      }
    }
  }
  float l2inv = ws[O_L2 + b];
  const float* flb = ws + O_FL + (size_t)b*CQ*NN;
  float fl[2][4];
  #pragma unroll
  for (int kt = 0; kt < 2; ++kt) {
    int kcol = kb*64 + kw*32 + kt*16 + row;
    #pragma unroll
    for (int rg = 0; rg < 4; ++rg)
      fl[kt][rg] = flb[(size_t)(quad*4 + rg)*NN + kcol];
  }
  #pragma unroll
  for (int mt = 0; mt < 4; ++mt) {
    int c = mbb*8 + mw*4 + mt;
    #pragma unroll
    for (int kt = 0; kt < 2; ++kt) {
      float s = fl[kt][0]*acc[mt][kt][0] + fl[kt][1]*acc[mt][kt][1]
              + fl[kt][2]*acc[mt][kt][2] + fl[kt][3]*acc[mt][kt][3];
      s += __shfl_xor(s, 32);
      s += __shfl_xor(s, 16);
      if (quad == 0) {
        int kcol = kb*64 + kw*32 + kt*16 + row;
        ws[O_XG + ((size_t)b*C4 + c)*NN + kcol] = s * l2inv;
      }
    }
  }
}

// K4: Fg = W_gcn xg + b_gcn
__global__ __launch_bounds__(256) void k4_out(const float* __restrict__ Wg,
                                              const float* __restrict__ bg,
                                              const float* __restrict__ ws,
                                              float* __restrict__ out) {
  int blk = blockIdx.x;             // b*4 + kc
  int b = blk >> 2, kc = blk & 3;
  int t = threadIdx.x;
  __shared__ float xg[C4][KT+1];
  __shared__ float wg[C4*C4];
  for (int e = t; e < C4*C4; e += 256) wg[e] = Wg[e];
  for (int e = t; e < C4*KT; e += 256) {
    int c = e >> 7, kk = e & (KT-1);
    xg[c][kk] = ws[O_XG + ((size_t)(b*C4 + c))*NN + kc*KT + kk];
  }
  __syncthreads();
  int kk = t & (KT-1);
  int ohalf = t >> 7;
  for (int oi = 0; oi < 32; ++oi) {
    int o = ohalf*32 + oi;
    float acc = bg[o];
    #pragma unroll
    for (int c = 0; c < C4; ++c) acc += wg[o*C4 + c] * xg[c][kk];
    out[((size_t)(b*C4 + o))*NN + kc*KT + kk] = acc;
  }
}

extern "C" void kernel_launch(void* const* d_in, const int* in_sizes, int n_in,
                              void* d_out, int out_size, void* d_ws, size_t ws_size,
                              hipStream_t stream) {
  const float* x  = (const float*)d_in[0];
  const float* Wc = (const float*)d_in[1];
  const float* bc = (const float*)d_in[2];
  const float* Wg = (const float*)d_in[3];
  const float* bg = (const float*)d_in[4];
  float* ws  = (float*)d_ws;
  float* out = (float*)d_out;

  hipMemsetAsync(ws + O_XX, 0, (2*B*CQ + 16)*sizeof(float), stream);

  k1_fc   <<<B*64,   256, 0, stream>>>(x, Wc, bc, ws);
  k1b_l2  <<<1,      128, 0, stream>>>(ws);
  k1c_flt <<<16,     256, 0, stream>>>(ws);
  k2_mfma <<<B*64,   256, 0, stream>>>(ws);
  k3_mfma <<<B*64,   256, 0, stream>>>(ws);
  k4_out  <<<B*4,    256, 0, stream>>>(Wg, bg, ws, out);
}

// Round 11
// 163.279 us; speedup vs baseline: 1.3958x; 1.1651x over previous
//
#include <hip/hip_runtime.h>
#include <hip/hip_bf16.h>
#include <math.h>

// Problem constants
#define B    8
#define C4   64
#define CQ   16
#define NN   512
#define L4   12
#define NCH1 8            // n's per k1 block
#define KT   128          // k-tile in final kernel

// workspace layout (float offsets)
#define O_TH   0                                   // Thi bf16 [b][m][n]      2097152
#define O_TL   (O_TH + (size_t)B*1024*NN/2)        // Tlo bf16 [b][m][n]      2097152
#define O_T2H  (O_TL + (size_t)B*1024*NN/2)        // Thi bf16 [b][n][m]      2097152
#define O_T2L  (O_T2H + (size_t)B*NN*1024/2)       // Tlo bf16 [b][n][m]      2097152
#define O_FL   (O_T2L + (size_t)B*NN*1024/2)       // Fl[b][q][k] fp32          65536
#define O_FLTH (O_FL + (size_t)B*CQ*NN)            // Flt hi bf16 [b][k][16]    32768
#define O_FLTL (O_FLTH + (size_t)B*NN*16/2)        // Flt lo bf16 [b][k][16]    32768
#define O_XX   (O_FLTL + (size_t)B*NN*16/2)        // [B][CQ]                     128
#define O_YY   (O_XX + B*CQ)                       //                             128
#define O_L2   (O_YY + B*CQ)                       // [B] 1/l2 (+pad)              16
#define O_AH   (O_L2 + 16)                         // Ahi bf16 [b][n][k]      1048576
#define O_AL   (O_AH + (size_t)B*NN*NN/2)          // Alo bf16 [b][n][k]      1048576
#define O_XG   (O_AL + (size_t)B*NN*NN/2)          // xg[b][c][k] fp32         262144

typedef __attribute__((ext_vector_type(8))) short short8;
typedef __attribute__((ext_vector_type(4))) float floatx4;
typedef __attribute__((ext_vector_type(16))) float floatx16;

__device__ inline void split2(float x0, float x1, uint& hw, uint& lw) {
  uint u0 = __float_as_uint(x0), u1 = __float_as_uint(x1);
  uint h0 = u0 >> 16, h1 = u1 >> 16;
  float r0 = x0 - __uint_as_float(h0 << 16);
  float r1 = x1 - __uint_as_float(h1 << 16);
  hw = h0 | (h1 << 16);
  lw = (__float_as_uint(r0) >> 16) | ((__float_as_uint(r1) >> 16) << 16);
}

// K1: Fc, Fl, norms, T bf16 split planes in BOTH layouts:
//  TH/TL [m][n] (for k3 staging), T2H/T2L [n][m] (for k2 A-frags).
__global__ __launch_bounds__(256) void k1_fc(const float* __restrict__ x,
                                             const float* __restrict__ Wc,
                                             const float* __restrict__ bc,
                                             float* __restrict__ ws) {
  int blk = blockIdx.x;                // b*64 + nchunk
  int b = blk >> 6;
  int n0 = (blk & 63) * NCH1;
  int t = threadIdx.x;
  __shared__ __align__(16) float xs[C4*NCH1*L4];   // [c][nl][j] 6144
  __shared__ float wcs[CQ*C4];                     // [q][c]
  __shared__ float bcs[CQ];
  __shared__ __align__(16) float fcs[NCH1*CQ*L4];  // [nl][q][j] 1536

  for (int e = t; e < CQ*C4; e += 256) wcs[e] = Wc[e];
  if (t < CQ) bcs[t] = bc[t];
  const float* xb = x + (size_t)b*C4*NN*L4 + (size_t)n0*L4;
  for (int f = t; f < (C4*NCH1*L4)/4; f += 256) {
    int c = f / (NCH1*L4/4);
    int r = f - c*(NCH1*L4/4);
    float4 v = *(const float4*)(xb + (size_t)c*NN*L4 + r*4);
    *(float4*)(xs + c*(NCH1*L4) + r*4) = v;
  }
  __syncthreads();
  for (int e = t; e < NCH1*CQ*L4; e += 256) {
    int nl = e / (CQ*L4);
    int rem = e - nl*(CQ*L4);
    int q = rem / L4, j = rem - q*L4;
    float acc = bcs[q];
    #pragma unroll
    for (int c = 0; c < C4; ++c) acc += wcs[q*C4 + c] * xs[c*(NCH1*L4) + nl*L4 + j];
    fcs[e] = acc;
    if (j == L4-1) ws[O_FL + ((size_t)b*CQ + q)*NN + n0 + nl] = acc;
  }
  __syncthreads();
  if (t < CQ) {
    float yy = 0.f, xx = 0.f;
    for (int nl = 0; nl < NCH1; ++nl) {
      #pragma unroll
      for (int j = 0; j < L4; ++j) { float v = fcs[nl*(CQ*L4) + t*L4 + j]; yy += v*v; }
      float w = fcs[nl*(CQ*L4) + t*L4 + (L4-1)];
      xx += w*w;
    }
    atomicAdd(ws + O_YY + b*CQ + t, yy);
    atomicAdd(ws + O_XX + b*CQ + t, xx);
  }
  {
    int c = t >> 2, q0 = (t & 3) * 4;
    float vals[4][NCH1];
    ushort* T2H = (ushort*)(ws + O_T2H);
    ushort* T2L = (ushort*)(ws + O_T2L);
    for (int nl = 0; nl < NCH1; ++nl) {
      float xr[L4];
      *(float4*)&xr[0] = *(const float4*)(xs + c*(NCH1*L4) + nl*L4);
      *(float4*)&xr[4] = *(const float4*)(xs + c*(NCH1*L4) + nl*L4 + 4);
      *(float4*)&xr[8] = *(const float4*)(xs + c*(NCH1*L4) + nl*L4 + 8);
      float tvp[4];
      #pragma unroll
      for (int i = 0; i < 4; ++i) {
        float a = 0.f;
        #pragma unroll
        for (int j = 0; j < L4; ++j) a += fcs[nl*(CQ*L4) + (q0+i)*L4 + j] * xr[j];
        tvp[i] = a;
        vals[i][nl] = a;
      }
      uint hw0, lw0, hw1, lw1;
      split2(tvp[0], tvp[1], hw0, lw0);
      split2(tvp[2], tvp[3], hw1, lw1);
      size_t off2 = ((size_t)b*NN + n0 + nl)*1024 + t*4;   // ushort index
      *(uint2*)(T2H + off2) = make_uint2(hw0, hw1);
      *(uint2*)(T2L + off2) = make_uint2(lw0, lw1);
    }
    ushort* TH = (ushort*)(ws + O_TH);
    ushort* TL = (ushort*)(ws + O_TL);
    #pragma unroll
    for (int i = 0; i < 4; ++i) {
      int m = c*16 + q0 + i;
      uint hw[4], lw[4];
      #pragma unroll
      for (int jj = 0; jj < 4; ++jj)
        split2(vals[i][2*jj], vals[i][2*jj+1], hw[jj], lw[jj]);
      size_t off = ((size_t)b*1024 + m)*NN + n0;   // ushort index
      *(uint4*)(TH + off) = make_uint4(hw[0], hw[1], hw[2], hw[3]);
      *(uint4*)(TL + off) = make_uint4(lw[0], lw[1], lw[2], lw[3]);
    }
  }
}

// K1b: l2inv[b]
__global__ void k1b_l2(float* __restrict__ ws) {
  int t = threadIdx.x;              // 128 threads = B*CQ
  __shared__ float s[B*CQ];
  s[t] = sqrtf(ws[O_XX + t]) * sqrtf(ws[O_YY + t]);
  __syncthreads();
  if (t < B) {
    float sum = 0.f;
    #pragma unroll
    for (int q = 0; q < CQ; ++q) sum += s[t*CQ + q];
    ws[O_L2 + t] = 1.0f / sum;
  }
}

// K1c: Flt[b][k][16] hi/lo bf16 (q contiguous, no pad). One thread per (b,k).
__global__ __launch_bounds__(256) void k1c_flt(float* __restrict__ ws) {
  int idx = blockIdx.x*256 + threadIdx.x;   // 0..4095 = b*512 + k
  int b = idx >> 9, k = idx & 511;
  const float* fl = ws + O_FL + (size_t)b*CQ*NN + k;
  ushort h[16], l[16];
  #pragma unroll
  for (int q = 0; q < CQ; ++q) {
    float v = fl[(size_t)q*NN];
    uint u = __float_as_uint(v);
    uint hh = u >> 16;
    float r = v - __uint_as_float(hh << 16);
    h[q] = (ushort)hh;
    l[q] = (ushort)(__float_as_uint(r) >> 16);
  }
  ushort* FH  = (ushort*)(ws + O_FLTH) + (size_t)idx*16;
  ushort* FLo = (ushort*)(ws + O_FLTL) + (size_t)idx*16;
  *(uint4*)(FH)      = *(uint4*)&h[0];
  *(uint4*)(FH + 8)  = *(uint4*)&h[8];
  *(uint4*)(FLo)     = *(uint4*)&l[0];
  *(uint4*)(FLo + 8) = *(uint4*)&l[8];
}

// K2 (pass 1, MFMA 32x32x16 split-bf16): per (b, 8-n chunk, khalf).
// K=16 = q exactly (no padding). Per n per wave: 2 c-tiles x 2 k-tiles,
// 3 split MFMAs each. Max over c = max over 32 rows (reg-permutation
// invariant) + shfl_xor(32). A = relu(tanh(m*l2inv)) -> split -> AH/AL.
// No LDS, no barriers. Grid 1024 = 4 blocks/CU for latency hiding.
__global__ __launch_bounds__(256, 4) void k2_mfma(float* __restrict__ ws) {
  int id = blockIdx.x;              // b*128 + nch*2 + kh
  int kh = id & 1;
  int nch = (id >> 1) & 63;
  int b = id >> 7;
  int t = threadIdx.x;
  int w = t >> 6, lane = t & 63;
  int col = lane & 31, half = lane >> 5;
  float l2inv = ws[O_L2 + b];
  const ushort* FltH = (const ushort*)(ws + O_FLTH);
  const ushort* FltL = (const ushort*)(ws + O_FLTL);
  // B-frags: 2 k-tiles of 32, hi+lo, resident
  short8 bhf[2], blf[2];
  int kcol[2];
  #pragma unroll
  for (int kt = 0; kt < 2; ++kt) {
    kcol[kt] = kh*256 + w*64 + kt*32 + col;
    size_t off = ((size_t)(b*NN + kcol[kt]))*16 + half*8;
    bhf[kt] = *(const short8*)(FltH + off);
    blf[kt] = *(const short8*)(FltL + off);
  }
  const ushort* T2H = (const ushort*)(ws + O_T2H) + ((size_t)b*NN + nch*8)*1024;
  const ushort* T2L = (const ushort*)(ws + O_T2L) + ((size_t)b*NN + nch*8)*1024;
  ushort* AH = (ushort*)(ws + O_AH) + ((size_t)b*NN + nch*8)*NN;
  ushort* AL = (ushort*)(ws + O_AL) + ((size_t)b*NN + nch*8)*NN;

  for (int i = 0; i < 8; ++i) {
    short8 ah[2], al[2];
    #pragma unroll
    for (int ct = 0; ct < 2; ++ct) {
      size_t off = (size_t)i*1024 + (ct*32 + col)*16 + half*8;
      ah[ct] = *(const short8*)(T2H + off);
      al[ct] = *(const short8*)(T2L + off);
    }
    floatx16 acc[2][2];
    #pragma unroll
    for (int ct = 0; ct < 2; ++ct)
      #pragma unroll
      for (int kt = 0; kt < 2; ++kt) {
        floatx16 a = {0.f,0.f,0.f,0.f,0.f,0.f,0.f,0.f,
                      0.f,0.f,0.f,0.f,0.f,0.f,0.f,0.f};
        a = __builtin_amdgcn_mfma_f32_32x32x16_bf16(ah[ct], bhf[kt], a, 0, 0, 0);
        a = __builtin_amdgcn_mfma_f32_32x32x16_bf16(ah[ct], blf[kt], a, 0, 0, 0);
        a = __builtin_amdgcn_mfma_f32_32x32x16_bf16(al[ct], bhf[kt], a, 0, 0, 0);
        acc[ct][kt] = a;
      }
    #pragma unroll
    for (int kt = 0; kt < 2; ++kt) {
      float m = acc[0][kt][0];
      #pragma unroll
      for (int ct = 0; ct < 2; ++ct)
        #pragma unroll
        for (int rg = 0; rg < 16; ++rg)
          if (ct + rg) m = fmaxf(m, acc[ct][kt][rg]);
      m = fmaxf(m, __shfl_xor(m, 32));
      float av = fmaxf(tanhf(m*l2inv), 0.f);
      uint u = __float_as_uint(av);
      uint hh = u >> 16;
      float r = av - __uint_as_float(hh << 16);
      ushort lv = (ushort)(__float_as_uint(r) >> 16);
      if (half == 0) {
        AH[(size_t)i*NN + kcol[kt]] = (ushort)hh;
        AL[(size_t)i*NN + kcol[kt]] = lv;
      }
    }
  }
}

// K3 (pass 2, MFMA split-bf16): unchanged (R9/R10 passed).
__global__ __launch_bounds__(256, 2) void k3_mfma(float* __restrict__ ws) {
  int id = blockIdx.x;             // b*64 + mbb*8 + kb
  int kb = id & 7;
  int mbb = (id >> 3) & 7;
  int b = id >> 6;
  int t = threadIdx.x;
  int lane = t & 63;
  int w = t >> 6;
  int mw = w >> 1, kw = w & 1;
  int row = lane & 15, quad = lane >> 4;

  __shared__ __align__(16) ushort Ah[128*32];
  __shared__ __align__(16) ushort Al[128*32];
  __shared__ __align__(16) ushort Bh[64*32];
  __shared__ __align__(16) ushort Bl[64*32];

  const ushort* TH = (const ushort*)(ws + O_TH) + ((size_t)b*1024 + mbb*128)*NN;
  const ushort* TL = (const ushort*)(ws + O_TL) + ((size_t)b*1024 + mbb*128)*NN;
  const ushort* AHp = (const ushort*)(ws + O_AH) + ((size_t)b*NN + kb*64)*NN;
  const ushort* ALp = (const ushort*)(ws + O_AL) + ((size_t)b*NN + kb*64)*NN;

  floatx4 acc[4][2];
  #pragma unroll
  for (int i = 0; i < 4; ++i)
    #pragma unroll
    for (int j = 0; j < 2; ++j) acc[i][j] = (floatx4){0.f, 0.f, 0.f, 0.f};

  for (int ksx = 0; ksx < 16; ++ksx) {
    int p0 = ksx*32;
    __syncthreads();
    #pragma unroll
    for (int i = 0; i < 2; ++i) {       // A: 128 rows x 32 n, hi+lo
      int f = t + 256*i;
      int m = f >> 2, seg = (f & 3) * 8;
      *(uint4*)(Ah + m*32 + seg) = *(const uint4*)(TH + (size_t)m*NN + p0 + seg);
      *(uint4*)(Al + m*32 + seg) = *(const uint4*)(TL + (size_t)m*NN + p0 + seg);
    }
    {                                   // B: 64 rows x 32 n, hi+lo
      int j = t >> 2, seg = (t & 3) * 8;
      *(uint4*)(Bh + j*32 + seg) = *(const uint4*)(AHp + (size_t)j*NN + p0 + seg);
      *(uint4*)(Bl + j*32 + seg) = *(const uint4*)(ALp + (size_t)j*NN + p0 + seg);
    }
    __syncthreads();
    short8 bh[2], bl[2];
    #pragma unroll
    for (int kt = 0; kt < 2; ++kt) {
      int jrow = kw*32 + kt*16 + row;
      bh[kt] = *(const short8*)(Bh + jrow*32 + quad*8);
      bl[kt] = *(const short8*)(Bl + jrow*32 + quad*8);
    }
    #pragma unroll
    for (int mt = 0; mt < 4; ++mt) {
      int mrow = mw*64 + mt*16 + row;
      short8 ah = *(const short8*)(Ah + mrow*32 + quad*8);
      short8 al = *(const short8*)(Al + mrow*32 + quad*8);
      #pragma unroll
      for (int kt = 0; kt < 2; ++kt) {
        acc[mt][kt] = __builtin_amdgcn_mfma_f32_16x16x32_bf16(ah, bh[kt], acc[mt][kt], 0, 0, 0);
        acc[mt][kt] = __builtin_amdgcn_mfma_f32_16x16x32_bf16(ah, bl[kt], acc[mt][kt], 0, 0, 0);
        acc[mt][kt] = __builtin_amdgcn_mfma_f32_16x16x32_bf16(al, bh[kt], acc[mt][kt], 0, 0, 0);
      }
    }
  }
  float l2inv = ws[O_L2 + b];
  const float* flb = ws + O_FL + (size_t)b*CQ*NN;
  float fl[2][4];
  #pragma unroll
  for (int kt = 0; kt < 2; ++kt) {
    int kcol = kb*64 + kw*32 + kt*16 + row;
    #pragma unroll
    for (int rg = 0; rg < 4; ++rg)
      fl[kt][rg] = flb[(size_t)(quad*4 + rg)*NN + kcol];
  }
  #pragma unroll
  for (int mt = 0; mt < 4; ++mt) {
    int c = mbb*8 + mw*4 + mt;
    #pragma unroll
    for (int kt = 0; kt < 2; ++kt) {
      float s = fl[kt][0]*acc[mt][kt][0] + fl[kt][1]*acc[mt][kt][1]
              + fl[kt][2]*acc[mt][kt][2] + fl[kt][3]*acc[mt][kt][3];
      s += __shfl_xor(s, 32);
      s += __shfl_xor(s, 16);
      if (quad == 0) {
        int kcol = kb*64 + kw*32 + kt*16 + row;
        ws[O_XG + ((size_t)b*C4 + c)*NN + kcol] = s * l2inv;
      }
    }
  }
}

// K4: Fg = W_gcn xg + b_gcn
__global__ __launch_bounds__(256) void k4_out(const float* __restrict__ Wg,
                                              const float* __restrict__ bg,
                                              const float* __restrict__ ws,
                                              float* __restrict__ out) {
  int blk = blockIdx.x;             // b*4 + kc
  int b = blk >> 2, kc = blk & 3;
  int t = threadIdx.x;
  __shared__ float xg[C4][KT+1];
  __shared__ float wg[C4*C4];
  for (int e = t; e < C4*C4; e += 256) wg[e] = Wg[e];
  for (int e = t; e < C4*KT; e += 256) {
    int c = e >> 7, kk = e & (KT-1);
    xg[c][kk] = ws[O_XG + ((size_t)(b*C4 + c))*NN + kc*KT + kk];
  }
  __syncthreads();
  int kk = t & (KT-1);
  int ohalf = t >> 7;
  for (int oi = 0; oi < 32; ++oi) {
    int o = ohalf*32 + oi;
    float acc = bg[o];
    #pragma unroll
    for (int c = 0; c < C4; ++c) acc += wg[o*C4 + c] * xg[c][kk];
    out[((size_t)(b*C4 + o))*NN + kc*KT + kk] = acc;
  }
}

extern "C" void kernel_launch(void* const* d_in, const int* in_sizes, int n_in,
                              void* d_out, int out_size, void* d_ws, size_t ws_size,
                              hipStream_t stream) {
  const float* x  = (const float*)d_in[0];
  const float* Wc = (const float*)d_in[1];
  const float* bc = (const float*)d_in[2];
  const float* Wg = (const float*)d_in[3];
  const float* bg = (const float*)d_in[4];
  float* ws  = (float*)d_ws;
  float* out = (float*)d_out;

  hipMemsetAsync(ws + O_XX, 0, (2*B*CQ + 16)*sizeof(float), stream);

  k1_fc   <<<B*64,   256, 0, stream>>>(x, Wc, bc, ws);
  k1b_l2  <<<1,      128, 0, stream>>>(ws);
  k1c_flt <<<16,     256, 0, stream>>>(ws);
  k2_mfma <<<B*128,  256, 0, stream>>>(ws);
  k3_mfma <<<B*64,   256, 0, stream>>>(ws);
  k4_out  <<<B*4,    256, 0, stream>>>(Wg, bg, ws, out);
}